// Round 6
// baseline (556.138 us; speedup 1.0000x reference)
//
#include <hip/hip_runtime.h>
#include <hip/hip_bf16.h>
#include <math.h>

#define DEV_INLINE __device__ __forceinline__

typedef __attribute__((ext_vector_type(8))) short short8;
typedef __attribute__((ext_vector_type(8))) unsigned short ushort8v;
typedef __attribute__((ext_vector_type(4))) float f32x4;

constexpr int H = 128, W = 128, C = 128, B = 4;
constexpr int HWc = H * W;        // 16384
constexpr int KK = 9;
constexpr int KT = 1184;          // cols row stride (37 chunks * 32)
constexpr int NTOT = 65536;       // B*H*W

DEV_INLINE unsigned short f2bf(float f) {
  union { float f; unsigned u; } v; v.f = f;
  unsigned r = v.u + 0x7FFFu + ((v.u >> 16) & 1u);   // RNE
  return (unsigned short)(r >> 16);
}
DEV_INLINE float ubits(unsigned u) {
  union { unsigned u; float f; } v; v.u = u; return v.f;
}
DEV_INLINE unsigned pack2bf(float a, float b) {
  float2 t; t.x = a; t.y = b;
  __hip_bfloat162 h = __float22bfloat162_rn(t);
  union { __hip_bfloat162 h; unsigned u; } c; c.h = h;
  return c.u;
}

// ---------------- mode-0 conv (offset/mask), R5 structure ----------------
// Block = 4 waves over 16 positions, K-split x4 (wave wv = channel group wv).
// wS = R5-swizzled [37][2][64][8]. Outputs fp32 offsets (18ch) + mask (9ch).
template<bool BN>
__global__ __launch_bounds__(256, 5)
void conv0(const unsigned short* __restrict__ src,
           const unsigned short* __restrict__ wS,
           const float* __restrict__ bias,
           float* __restrict__ outOff, float* __restrict__ outMsk)
{
  __shared__ float red[3 * 2 * 4 * 64];
  const int tid  = threadIdx.x;
  const int lane = tid & 63;
  const int m16  = lane & 15;
  const int q    = lane >> 4;
  const int wv   = tid >> 6;

  const int raw  = blockIdx.x;
  const int xcd  = raw & 7;
  const int slot = raw >> 3;
  const int b    = xcd >> 1;
  const int hy   = ((xcd & 1) << 6) | (slot >> 3);
  const int hx0  = (slot & 7) << 4;
  const unsigned short* __restrict__ srcB = src + (size_t)b * C * HWc;

  f32x4 acc[2];
  acc[0] = (f32x4){0.f, 0.f, 0.f, 0.f};
  acc[1] = (f32x4){0.f, 0.f, 0.f, 0.f};

  const int hx = hx0 + m16;
  const unsigned short* __restrict__ pl = srcB + (size_t)((wv << 5) + (q << 3)) * HWc;

  for (int tap = 0; tap < 9; ++tap) {
    union { unsigned u[4]; short8 s; } bfr;
    const int ky = tap / 3, kx = tap - 3 * (tap / 3);
    const int iy = hy + ky - 1;
    const int ix = hx + kx - 1;
    const bool vok = ((unsigned)iy < (unsigned)H) && ((unsigned)ix < (unsigned)W);
    const unsigned short* qp = pl + (iy * W + ix);
    #pragma unroll
    for (int t = 0; t < 4; ++t) {
      const unsigned short lo = vok ? qp[(size_t)(2 * t) * HWc]     : (unsigned short)0;
      const unsigned short hi = vok ? qp[(size_t)(2 * t + 1) * HWc] : (unsigned short)0;
      bfr.u[t] = (unsigned)lo | ((unsigned)hi << 16);
    }
    const int ch = wv * 9 + tap;
    const unsigned short* ap = wS + ((size_t)ch * 2 * 64 + lane) * 8;
    acc[0] = __builtin_amdgcn_mfma_f32_16x16x32_bf16(*(const short8*)(ap), bfr.s, acc[0], 0, 0, 0);
    acc[1] = __builtin_amdgcn_mfma_f32_16x16x32_bf16(*(const short8*)(ap + 512), bfr.s, acc[1], 0, 0, 0);
  }
  if constexpr (BN) {
    if (wv == 3) {
      union { unsigned u[4]; short8 s; } bfr;
      float sv[8];
      #pragma unroll
      for (int j = 0; j < 8; ++j) {
        const int kj = (q << 3) + j;
        float s = 0.f;
        if (kj < KK) {
          const int ky = kj / 3, kx = kj - 3 * (kj / 3);
          const int iy = hy + ky - 1, ix = hx + kx - 1;
          s = (((unsigned)iy < (unsigned)H) && ((unsigned)ix < (unsigned)W)) ? 1.f : 0.f;
        }
        sv[j] = s;
      }
      #pragma unroll
      for (int t = 0; t < 4; ++t) bfr.u[t] = pack2bf(sv[2 * t], sv[2 * t + 1]);
      const unsigned short* ap = wS + ((size_t)36 * 2 * 64 + lane) * 8;
      acc[0] = __builtin_amdgcn_mfma_f32_16x16x32_bf16(*(const short8*)(ap), bfr.s, acc[0], 0, 0, 0);
      acc[1] = __builtin_amdgcn_mfma_f32_16x16x32_bf16(*(const short8*)(ap + 512), bfr.s, acc[1], 0, 0, 0);
    }
  }
  if (wv != 0) {
    float* r = red + (size_t)(wv - 1) * 512;
    #pragma unroll
    for (int ot = 0; ot < 2; ++ot)
      #pragma unroll
      for (int rg = 0; rg < 4; ++rg)
        r[(ot * 4 + rg) * 64 + lane] = acc[ot][rg];
  }
  __syncthreads();
  if (wv == 0) {
    #pragma unroll
    for (int ot = 0; ot < 2; ++ot) {
      #pragma unroll
      for (int rg = 0; rg < 4; ++rg) {
        const int idx = (ot * 4 + rg) * 64 + lane;
        const float vv = acc[ot][rg] + red[idx] + red[512 + idx] + red[1024 + idx];
        const int o = ot * 16 + (q << 2) + rg;
        if (o < 18) {
          outOff[((size_t)(b * 18 + o) * H + hy) * W + hx] = vv + bias[o];
        } else if (o < 27) {
          const float z = vv + bias[o];
          outMsk[((size_t)(b * 9 + (o - 18)) * H + hy) * W + hx] = 2.f / (1.f + expf(-z));
        }
      }
    }
  }
}

// ---------------- bilinear table build ----------------
// Per (tap, n): clamped row-pair bases + 4 folded fp32 weights.
// BN: also writes cols BN rows (k = 1152+tap) = sum of bilinear weights.
template<bool BN>
__global__ __launch_bounds__(256, 4)
void tblk(const float* __restrict__ offs, const float* __restrict__ msk,
          unsigned* __restrict__ tIdx, float4* __restrict__ tW,
          unsigned short* __restrict__ colsT, int n0, int NC)
{
  const int tap = blockIdx.y;
  const int nl  = blockIdx.x * 256 + threadIdx.x;
  const int n   = n0 + nl;
  const int b   = n >> 14;
  const int pos = n & 16383;
  const int hy  = pos >> 7, hx = pos & 127;
  const int ky  = tap / 3, kx = tap - 3 * (tap / 3);
  const size_t ob = ((size_t)(b * 18 + 2 * tap) * H + hy) * W + hx;
  const float oy = offs[ob];
  const float ox = offs[ob + (size_t)HWc];
  const float mv = msk[((size_t)(b * 9 + tap) * H + hy) * W + hx];
  const float py = (float)(hy - 1 + ky) + oy;
  const float px = (float)(hx - 1 + kx) + ox;
  const float fy = floorf(py), fx = floorf(px);
  const float ay = py - fy, ax = px - fx;
  const int y0 = (int)fy, x0 = (int)fx;
  const int y1 = y0 + 1, x1 = x0 + 1;
  const float wyt = (1.f - ay) * (((unsigned)y0 < (unsigned)H) ? 1.f : 0.f);
  const float wyb = ay * (((unsigned)y1 < (unsigned)H) ? 1.f : 0.f);
  const int y0c = min(max(y0, 0), H - 1), y1c = min(max(y1, 0), H - 1);
  const int bx  = min(max(x0, 0), W - 2);
  float wA = 0.f, wB = 0.f;
  if (x0 == bx)          { wA = 1.f - ax; wB = ax; }
  else if (x1 == bx)     { wA = ax; }
  else if (x0 == bx + 1) { wB = 1.f - ax; }
  tIdx[tap * NC + nl] = (unsigned)(y0c * W + bx) | ((unsigned)(y1c * W + bx) << 16);
  const float4 wt = make_float4(mv * wyt * wA, mv * wyt * wB,
                                mv * wyb * wA, mv * wyb * wB);
  tW[tap * NC + nl] = wt;
  if constexpr (BN)
    colsT[(size_t)nl * KT + 1152 + tap] = f2bf(wt.x + wt.y + wt.z + wt.w);
}

// ---------------- phase A: materialize deformed columns ----------------
// Thread = (ch-octet, tap, n): 16 row-pair gathers -> one 16-B store.
__global__ __launch_bounds__(256, 4)
void phaseA(const unsigned short* __restrict__ src,
            const unsigned* __restrict__ tIdx, const float4* __restrict__ tW,
            unsigned short* __restrict__ colsT, int n0, int NC)
{
  const int coct = blockIdx.x;
  const int tap  = blockIdx.y;
  const int nl   = blockIdx.z * 256 + threadIdx.x;
  const int n    = n0 + nl;
  const int b    = n >> 14;
  const int e    = tap * NC + nl;
  const unsigned id = tIdx[e];
  const float4 wt = tW[e];
  const int rA = id & 0xFFFF, rB = id >> 16;
  const unsigned short* __restrict__ pl = src + ((size_t)(b * C) + coct * 8) * HWc;
  float sv[8];
  #pragma unroll
  for (int j = 0; j < 8; ++j) {
    unsigned a, c;
    __builtin_memcpy(&a, pl + (size_t)j * HWc + rA, 4);
    __builtin_memcpy(&c, pl + (size_t)j * HWc + rB, 4);
    sv[j] = wt.x * ubits(a << 16) + wt.y * ubits(a & 0xFFFF0000u)
          + wt.z * ubits(c << 16) + wt.w * ubits(c & 0xFFFF0000u);
  }
  union { unsigned u[4]; ushort8v v; } o;
  #pragma unroll
  for (int t = 0; t < 4; ++t) o.u[t] = pack2bf(sv[2 * t], sv[2 * t + 1]);
  *(ushort8v*)(colsT + (size_t)nl * KT + tap * 128 + coct * 8) = o.v;
}

// ---------------- phase B: dense GEMM over materialized columns ----------------
// Block 256 thr = 4 waves x 16 positions. Weights [128][1184] LDS double-buffered
// (80-B padded rows, 1 barrier/chunk). Cols read directly as 16-B/lane B-frags.
// MODE 1: PReLU -> bf16. MODE 2: BN2 + fp32 residual -> fp32.
template<int MODE, bool BN>
__global__ __launch_bounds__(256, 4)
void phaseB(const unsigned short* __restrict__ colsT,
            const unsigned short* __restrict__ wT,    // [128][1184]
            const float* __restrict__ pA, const float* __restrict__ pB,
            const float* __restrict__ pM, const float* __restrict__ pV,
            const float* __restrict__ resid,
            unsigned short* __restrict__ outh, float* __restrict__ outf,
            int n0)
{
  constexpr int NCH = BN ? 37 : 36;
  __shared__ __attribute__((aligned(16))) unsigned short wbuf[2][128 * 40];
  const int tid  = threadIdx.x;
  const int lane = tid & 63;
  const int m16  = lane & 15;
  const int q    = lane >> 4;
  const int wv   = tid >> 6;
  const int nl0  = blockIdx.x * 64 + wv * 16;

  const int so = tid >> 1;
  const int sh = (tid & 1) << 4;
  const unsigned short* sgp = wT + (size_t)so * KT + sh;
  unsigned short* sd0 = &wbuf[0][0] + so * 40 + sh;

  // prologue: stage chunk 0 into buf 0
  {
    const short8 r0 = *(const short8*)(sgp);
    const short8 r1 = *(const short8*)(sgp + 8);
    *(short8*)(sd0) = r0;
    *(short8*)(sd0 + 8) = r1;
  }
  __syncthreads();

  f32x4 acc[8];
  #pragma unroll
  for (int i = 0; i < 8; ++i) acc[i] = (f32x4){0.f, 0.f, 0.f, 0.f};

  const unsigned short* __restrict__ bp = colsT + (size_t)(nl0 + m16) * KT + q * 8;

  for (int ch = 0; ch < NCH; ++ch) {
    const short8 bfr = *(const short8*)(bp + ch * 32);
    short8 nr0, nr1;
    if (ch + 1 < NCH) {
      nr0 = *(const short8*)(sgp + (ch + 1) * 32);
      nr1 = *(const short8*)(sgp + (ch + 1) * 32 + 8);
    }
    const unsigned short* rb = &wbuf[ch & 1][0];
    #pragma unroll
    for (int ot = 0; ot < 8; ++ot) {
      const short8 afr = *(const short8*)(rb + (ot * 16 + m16) * 40 + q * 8);
      acc[ot] = __builtin_amdgcn_mfma_f32_16x16x32_bf16(afr, bfr, acc[ot], 0, 0, 0);
    }
    if (ch + 1 < NCH) {
      unsigned short* wd = &wbuf[(ch + 1) & 1][0] + so * 40 + sh;
      *(short8*)(wd) = nr0;
      *(short8*)(wd + 8) = nr1;
    }
    __syncthreads();
  }

  // epilogue: D col = m16 -> position, row = q*4+rg -> o
  const int n  = n0 + nl0 + m16;
  const int bb = n >> 14;
  const int pos = n & 16383;
  #pragma unroll
  for (int ot = 0; ot < 8; ++ot) {
    #pragma unroll
    for (int rg = 0; rg < 4; ++rg) {
      const int o = ot * 16 + (q << 2) + rg;
      const float vv = acc[ot][rg];
      const size_t oi = ((size_t)(bb * C + o) << 14) + pos;
      if constexpr (MODE == 1) {
        const float a = pA[o];
        outh[oi] = f2bf(vv > 0.f ? vv : a * vv);
      } else {
        const float s  = pA[o] * rsqrtf(pV[o] + 1e-5f);
        const float sh2 = pB[o] - pM[o] * s;
        outf[oi] = vv * s + sh2 + resid[oi];
      }
    }
  }
}

__global__ void xcvt(const float* __restrict__ x, unsigned short* __restrict__ xb)
{
  const int i = blockIdx.x * 256 + threadIdx.x;
  const float4 v = ((const float4*)x)[i];
  ushort4 o;
  o.x = f2bf(v.x); o.y = f2bf(v.y); o.z = f2bf(v.z); o.w = f2bf(v.w);
  *(ushort4*)(xb + (size_t)i * 4) = o;
}

// wb: [o][1184] row-major, k = tap*128 + c, BN1 scale folded (layer 1),
//     BN-shift column at k=1152..1160, zeros 1161..1183.
// wom: R5-swizzle [37][2][64][8] for conv0.
__global__ void prep4(const float* __restrict__ w1, const float* __restrict__ w2,
                      const float* __restrict__ ow1, const float* __restrict__ mw1,
                      const float* __restrict__ ob1, const float* __restrict__ mb1,
                      const float* __restrict__ ow2, const float* __restrict__ mw2,
                      const float* __restrict__ ob2, const float* __restrict__ mb2,
                      const float* __restrict__ g, const float* __restrict__ bb,
                      const float* __restrict__ m, const float* __restrict__ v,
                      unsigned short* __restrict__ wb1, unsigned short* __restrict__ wb2,
                      unsigned short* __restrict__ wom1, unsigned short* __restrict__ wom2,
                      float* __restrict__ bias1, float* __restrict__ bias2)
{
  const int i = blockIdx.x * 256 + threadIdx.x;
  if (i < 128 * KT) {
    const int o = i / KT, k = i - o * KT;
    unsigned short v1 = 0, v2 = 0;
    if (k < 1152) {
      const int tap = k >> 7, c = k & 127;
      const float s = g[c] * rsqrtf(v[c] + 1e-5f);
      v1 = f2bf(w1[(size_t)(o * 128 + c) * 9 + tap] * s);
      v2 = f2bf(w2[(size_t)(o * 128 + c) * 9 + tap]);
    } else if (k < 1152 + KK) {
      const int kk = k - 1152;
      float acc = 0.f;
      for (int c = 0; c < 128; ++c) {
        const float s  = g[c] * rsqrtf(v[c] + 1e-5f);
        const float sh = bb[c] - m[c] * s;
        acc += w1[(size_t)(o * 128 + c) * 9 + kk] * sh;
      }
      v1 = f2bf(acc);
    }
    wb1[i] = v1; wb2[i] = v2;
  }
  if (i < 32 * KT) {
    const int lane = (i >> 3) & 63, ot = (i >> 9) & 1, ch = i >> 10;
    const int o  = ot * 16 + (lane & 15);
    const int kp = ch * 32 + ((lane >> 4) << 3) + (i & 7);
    unsigned short v1 = 0, v2 = 0;
    if (kp < 1152) {
      const int chn = kp >> 5, jj = kp & 31;
      const int cg = chn / 9, tap = chn - 9 * cg;
      const int c = (cg << 5) + jj;
      const float s = g[c] * rsqrtf(v[c] + 1e-5f);
      if (o < 18) {
        v1 = f2bf(ow1[(size_t)(o * 128 + c) * 9 + tap] * s);
        v2 = f2bf(ow2[(size_t)(o * 128 + c) * 9 + tap]);
      } else if (o < 27) {
        v1 = f2bf(mw1[(size_t)((o - 18) * 128 + c) * 9 + tap] * s);
        v2 = f2bf(mw2[(size_t)((o - 18) * 128 + c) * 9 + tap]);
      }
    } else if (kp < 1152 + KK && o < 27) {
      const int kk = kp - 1152;
      const float* wsrc = (o < 18) ? ow1 + (size_t)o * 1152
                                   : mw1 + (size_t)(o - 18) * 1152;
      float acc = 0.f;
      for (int c = 0; c < 128; ++c) {
        const float s  = g[c] * rsqrtf(v[c] + 1e-5f);
        const float sh = bb[c] - m[c] * s;
        acc += wsrc[(size_t)c * 9 + kk] * sh;
      }
      v1 = f2bf(acc);
    }
    wom1[i] = v1; wom2[i] = v2;
  }
  if (i < 32) {
    float b1 = 0.f, b2 = 0.f;
    if (i < 18)      { b1 = ob1[i];      b2 = ob2[i]; }
    else if (i < 27) { b1 = mb1[i - 18]; b2 = mb2[i - 18]; }
    bias1[i] = b1; bias2[i] = b2;
  }
}

extern "C" void kernel_launch(void* const* d_in, const int* in_sizes, int n_in,
                              void* d_out, int out_size, void* d_ws, size_t ws_size,
                              hipStream_t stream)
{
  const float* x     = (const float*)d_in[0];
  const float* bn1g  = (const float*)d_in[1];
  const float* bn1b  = (const float*)d_in[2];
  const float* bn1m  = (const float*)d_in[3];
  const float* bn1v  = (const float*)d_in[4];
  const float* ow1   = (const float*)d_in[5];
  const float* ob1   = (const float*)d_in[6];
  const float* mw1   = (const float*)d_in[7];
  const float* mb1   = (const float*)d_in[8];
  const float* w1    = (const float*)d_in[9];
  const float* alpha = (const float*)d_in[10];
  const float* ow2   = (const float*)d_in[11];
  const float* ob2   = (const float*)d_in[12];
  const float* mw2   = (const float*)d_in[13];
  const float* mb2   = (const float*)d_in[14];
  const float* w2    = (const float*)d_in[15];
  const float* bn2g  = (const float*)d_in[16];
  const float* bn2b  = (const float*)d_in[17];
  const float* bn2m  = (const float*)d_in[18];
  const float* bn2v  = (const float*)d_in[19];
  float* out = (float*)d_out;

  char* wsp = (char*)d_ws;
  unsigned short* xbf  = (unsigned short*)(wsp);             // 16777216
  unsigned short* r2bf = (unsigned short*)(wsp + 16777216);  // 16777216
  float* offb = (float*)(wsp + 33554432);                    // 4718592
  float* mskb = (float*)(wsp + 38273024);                    // 2359296
  unsigned short* wb1  = (unsigned short*)(wsp + 40632320);  // 303104
  unsigned short* wb2  = (unsigned short*)(wsp + 40935424);  // 303104
  unsigned short* wom1 = (unsigned short*)(wsp + 41238528);  // 75776
  unsigned short* wom2 = (unsigned short*)(wsp + 41314304);  // 75776
  float* bias1 = (float*)(wsp + 41390080);                   // 128
  float* bias2 = (float*)(wsp + 41390208);                   // 128
  const size_t fixedEnd = 41390336;

  // adaptive batch chunking for cols buffer
  int NP = 8;
  for (int cand = 1; cand <= 8; cand <<= 1) {
    const size_t NCc = NTOT / cand;
    const size_t need = fixedEnd + (size_t)9 * NCc * 4 + (size_t)9 * NCc * 16
                      + (size_t)NCc * KT * 2;
    if (need <= ws_size) { NP = cand; break; }
  }
  const int NC = NTOT / NP;
  unsigned* tIdx = (unsigned*)(wsp + fixedEnd);
  float4*   tW   = (float4*)(wsp + fixedEnd + (size_t)9 * NC * 4);
  unsigned short* colsT = (unsigned short*)(wsp + fixedEnd + (size_t)9 * NC * 4
                                            + (size_t)9 * NC * 16);

  xcvt<<<8192, 256, 0, stream>>>(x, xbf);
  prep4<<<(128 * KT + 255) / 256, 256, 0, stream>>>(
      w1, w2, ow1, mw1, ob1, mb1, ow2, mw2, ob2, mb2,
      bn1g, bn1b, bn1m, bn1v, wb1, wb2, wom1, wom2, bias1, bias2);

  // ---- layer 1 ----
  conv0<true><<<4096, 256, 0, stream>>>(xbf, wom1, bias1, offb, mskb);
  for (int p = 0; p < NP; ++p) {
    const int n0 = p * NC;
    tblk<true><<<dim3(NC / 256, 9), 256, 0, stream>>>(offb, mskb, tIdx, tW, colsT, n0, NC);
    phaseA<<<dim3(16, 9, NC / 256), 256, 0, stream>>>(xbf, tIdx, tW, colsT, n0, NC);
    phaseB<1, true><<<NC / 64, 256, 0, stream>>>(colsT, wb1, alpha,
        nullptr, nullptr, nullptr, nullptr, r2bf, nullptr, n0);
  }

  // ---- layer 2 ----
  conv0<false><<<4096, 256, 0, stream>>>(r2bf, wom2, bias2, offb, mskb);
  for (int p = 0; p < NP; ++p) {
    const int n0 = p * NC;
    tblk<false><<<dim3(NC / 256, 9), 256, 0, stream>>>(offb, mskb, tIdx, tW, colsT, n0, NC);
    phaseA<<<dim3(16, 9, NC / 256), 256, 0, stream>>>(r2bf, tIdx, tW, colsT, n0, NC);
    phaseB<2, false><<<NC / 64, 256, 0, stream>>>(colsT, wb2, bn2g,
        bn2b, bn2m, bn2v, x, nullptr, out, n0);
  }
}

// Round 7
// 372.993 us; speedup vs baseline: 1.4910x; 1.4910x over previous
//
#include <hip/hip_runtime.h>
#include <hip/hip_bf16.h>
#include <math.h>

#define DEV_INLINE __device__ __forceinline__

typedef __attribute__((ext_vector_type(8))) short short8;
typedef __attribute__((ext_vector_type(8))) unsigned short ushort8v;
typedef __attribute__((ext_vector_type(4))) float f32x4;

constexpr int H = 128, W = 128, C = 128, B = 4;
constexpr int HWc = H * W;        // 16384
constexpr int KK = 9;
constexpr int KT2 = 1184;         // 37 chunks * 32

DEV_INLINE unsigned short f2bf(float f) {
  union { float f; unsigned u; } v; v.f = f;
  unsigned r = v.u + 0x7FFFu + ((v.u >> 16) & 1u);   // RNE
  return (unsigned short)(r >> 16);
}
DEV_INLINE float ubits(unsigned u) {
  union { unsigned u; float f; } v; v.u = u; return v.f;
}
DEV_INLINE float bfu(unsigned short u) { return ubits(((unsigned)u) << 16); }
DEV_INLINE unsigned pack2bf(float a, float b) {
  float2 t; t.x = a; t.y = b;
  __hip_bfloat162 h = __float22bfloat162_rn(t);
  union { __hip_bfloat162 h; unsigned u; } c; c.h = h;
  return c.u;
}

// Fused implicit GEMM over NHWC bf16 source. One wave per block; wave owns 32
// positions (row segment) = 2 MFMA B-groups. Full-K per wave: chunk ch<36:
// tap = ch>>2, cg = ch&3, k = q*8+j -> channel cg*32+q*8+j at tap. ch 36 (BN,
// layer1): B col = sum of bilinear weights (deform) / validity (plain); A rows
// = BN-shift columns. A-frags from swizzled global table wS[ch][NT][64][8]
// (L1-hot, reused across both position groups). Gathers: 4 corners x 16 B
// contiguous per lane (NHWC); x-pair weights folded with clamp/validity.
// MODE 0: plain conv O=32 -> fp32 offsets+mask. MODE 1: deform O=128, PReLU
// -> NHWC bf16. MODE 2: deform O=128, BN2 + NCHW fp32 residual -> NCHW fp32.
template<int MODE, bool BN>
__global__ __launch_bounds__(64, 2)
void gemm7(const unsigned short* __restrict__ src,     // NHWC bf16 (B,H,W,C)
           const unsigned short* __restrict__ wS,      // [37][NT][64][8]
           const float* __restrict__ offs,             // (B,18,H,W) fp32
           const float* __restrict__ msk,              // (B,9,H,W) fp32
           const float* __restrict__ pA, const float* __restrict__ pB,
           const float* __restrict__ pM, const float* __restrict__ pV,
           const float* __restrict__ resid,
           float* __restrict__ outf,                   // MODE0 offs / MODE2 out
           unsigned short* __restrict__ outh,          // MODE1 NHWC bf16
           float* __restrict__ out1)                   // MODE0 mask
{
  constexpr int NT = (MODE == 0) ? 2 : 8;
  __shared__ ushort2 sId[(MODE != 0) ? KK * 32 : 1];
  __shared__ float4  sWt[(MODE != 0) ? KK * 32 : 1];

  const int lane = threadIdx.x;
  const int m16  = lane & 15;
  const int q    = lane >> 4;

  const int raw  = blockIdx.x;                // 2048 blocks
  const int xcd  = raw & 7;
  const int slot = raw >> 3;                  // [0,256)
  const int b    = xcd >> 1;
  const int hy   = ((xcd & 1) << 6) | (slot >> 2);
  const int hx0  = (slot & 3) << 5;           // 32-wide segment
  const unsigned short* __restrict__ srcB = src + ((size_t)b << 14) * C;

  // ---- bilinear table: 9 taps x 32 positions ----
  if constexpr (MODE != 0) {
    for (int e = lane; e < KK * 32; e += 64) {
      const int tap = e >> 5;
      const int hx  = hx0 + (e & 31);
      const int ky  = tap / 3, kx = tap - 3 * (tap / 3);
      const size_t ob = ((size_t)(b * 18 + 2 * tap) * H + hy) * W + hx;
      const float oy = offs[ob];
      const float ox = offs[ob + (size_t)HWc];
      const float mv = msk[((size_t)(b * 9 + tap) * H + hy) * W + hx];
      const float py = (float)(hy - 1 + ky) + oy;
      const float px = (float)(hx - 1 + kx) + ox;
      const float fy = floorf(py), fx = floorf(px);
      const float ay = py - fy, ax = px - fx;
      const int y0 = (int)fy, x0 = (int)fx;
      const int y1 = y0 + 1, x1 = x0 + 1;
      const float wyt = (1.f - ay) * (((unsigned)y0 < (unsigned)H) ? 1.f : 0.f);
      const float wyb = ay * (((unsigned)y1 < (unsigned)H) ? 1.f : 0.f);
      const int y0c = min(max(y0, 0), H - 1), y1c = min(max(y1, 0), H - 1);
      const int bx  = min(max(x0, 0), W - 2);
      float wA = 0.f, wB = 0.f;
      if (x0 == bx)          { wA = 1.f - ax; wB = ax; }
      else if (x1 == bx)     { wA = ax; }
      else if (x0 == bx + 1) { wB = 1.f - ax; }
      sId[e] = make_ushort2((unsigned short)(y0c * W + bx),
                            (unsigned short)(y1c * W + bx));
      sWt[e] = make_float4(mv * wyt * wA, mv * wyt * wB,
                           mv * wyb * wA, mv * wyb * wB);
    }
    __syncthreads();
  }

  f32x4 acc[2][NT];
  #pragma unroll
  for (int g = 0; g < 2; ++g)
    #pragma unroll
    for (int i = 0; i < NT; ++i) acc[g][i] = (f32x4){0.f, 0.f, 0.f, 0.f};

  const int choff = q << 3;   // within-chunk channel octet (x2 for cg later)

  for (int ch = 0; ch < 36; ++ch) {
    const int tap = ch >> 2, cg = ch & 3;
    const int cbase = (cg << 5) + choff;
    const unsigned short* ap = wS + ((size_t)ch * NT * 64 + lane) * 8;
    short8 afr[NT];
    #pragma unroll
    for (int ot = 0; ot < NT; ++ot)
      afr[ot] = *(const short8*)(ap + (size_t)ot * 512);

    #pragma unroll
    for (int g = 0; g < 2; ++g) {
      union { unsigned u[4]; short8 s; } bfr;
      if constexpr (MODE != 0) {
        const int e = (tap << 5) + (g << 4) + m16;
        const ushort2 id = sId[e];
        const float4  wt = sWt[e];
        const unsigned short* pT = srcB + ((size_t)id.x * C + cbase);
        const unsigned short* pBt = srcB + ((size_t)id.y * C + cbase);
        const ushort8v TL = *(const ushort8v*)(pT);
        const ushort8v TR = *(const ushort8v*)(pT + C);
        const ushort8v BL = *(const ushort8v*)(pBt);
        const ushort8v BR = *(const ushort8v*)(pBt + C);
        float sv[8];
        #pragma unroll
        for (int j = 0; j < 8; ++j)
          sv[j] = wt.x * bfu(TL[j]) + wt.y * bfu(TR[j])
                + wt.z * bfu(BL[j]) + wt.w * bfu(BR[j]);
        #pragma unroll
        for (int t = 0; t < 4; ++t) bfr.u[t] = pack2bf(sv[2 * t], sv[2 * t + 1]);
      } else {
        const int ky = tap / 3, kx = tap - 3 * (tap / 3);
        const int iy = hy + ky - 1;
        const int ix = hx0 + (g << 4) + m16 + kx - 1;
        const bool vok = ((unsigned)iy < (unsigned)H) && ((unsigned)ix < (unsigned)W);
        const int rb = vok ? (iy * W + ix) : 0;
        const ushort8v v = *(const ushort8v*)(srcB + ((size_t)rb * C + cbase));
        #pragma unroll
        for (int t = 0; t < 4; ++t) {
          const unsigned short lo = vok ? v[2 * t]     : (unsigned short)0;
          const unsigned short hi = vok ? v[2 * t + 1] : (unsigned short)0;
          bfr.u[t] = (unsigned)lo | ((unsigned)hi << 16);
        }
      }
      #pragma unroll
      for (int ot = 0; ot < NT; ++ot)
        acc[g][ot] = __builtin_amdgcn_mfma_f32_16x16x32_bf16(afr[ot], bfr.s, acc[g][ot], 0, 0, 0);
    }
  }

  if constexpr (BN) {   // chunk 36: BN-shift column
    const unsigned short* ap = wS + ((size_t)36 * NT * 64 + lane) * 8;
    short8 afr[NT];
    #pragma unroll
    for (int ot = 0; ot < NT; ++ot)
      afr[ot] = *(const short8*)(ap + (size_t)ot * 512);
    #pragma unroll
    for (int g = 0; g < 2; ++g) {
      union { unsigned u[4]; short8 s; } bfr;
      float sv[8];
      #pragma unroll
      for (int j = 0; j < 8; ++j) {
        const int kj = (q << 3) + j;
        float s = 0.f;
        if (kj < KK) {
          if constexpr (MODE != 0) {
            const float4 wt = sWt[(kj << 5) + (g << 4) + m16];
            s = wt.x + wt.y + wt.z + wt.w;
          } else {
            const int ky = kj / 3, kx = kj - 3 * (kj / 3);
            const int iy = hy + ky - 1;
            const int ix = hx0 + (g << 4) + m16 + kx - 1;
            s = (((unsigned)iy < (unsigned)H) && ((unsigned)ix < (unsigned)W)) ? 1.f : 0.f;
          }
        }
        sv[j] = s;
      }
      #pragma unroll
      for (int t = 0; t < 4; ++t) bfr.u[t] = pack2bf(sv[2 * t], sv[2 * t + 1]);
      #pragma unroll
      for (int ot = 0; ot < NT; ++ot)
        acc[g][ot] = __builtin_amdgcn_mfma_f32_16x16x32_bf16(afr[ot], bfr.s, acc[g][ot], 0, 0, 0);
    }
  }

  // ---- epilogue: D col = m16 -> position, row = q*4+rg -> o ----
  #pragma unroll
  for (int g = 0; g < 2; ++g) {
    const int hx = hx0 + (g << 4) + m16;
    const int n  = (b << 14) + hy * W + hx;     // global position
    #pragma unroll
    for (int ot = 0; ot < NT; ++ot) {
      if constexpr (MODE == 1) {
        // PReLU -> NHWC bf16, 8-B store of 4 consecutive channels
        unsigned u0, u1;
        {
          const float a0 = pA[ot * 16 + (q << 2) + 0];
          const float a1 = pA[ot * 16 + (q << 2) + 1];
          const float a2 = pA[ot * 16 + (q << 2) + 2];
          const float a3 = pA[ot * 16 + (q << 2) + 3];
          const float v0 = acc[g][ot][0], v1 = acc[g][ot][1];
          const float v2 = acc[g][ot][2], v3 = acc[g][ot][3];
          u0 = pack2bf(v0 > 0.f ? v0 : a0 * v0, v1 > 0.f ? v1 : a1 * v1);
          u1 = pack2bf(v2 > 0.f ? v2 : a2 * v2, v3 > 0.f ? v3 : a3 * v3);
        }
        uint2 st; st.x = u0; st.y = u1;
        *(uint2*)(outh + (size_t)n * C + ot * 16 + (q << 2)) = st;
      } else {
        #pragma unroll
        for (int rg = 0; rg < 4; ++rg) {
          const int o = ot * 16 + (q << 2) + rg;
          const float vv = acc[g][ot][rg];
          if constexpr (MODE == 0) {
            if (o < 18) {
              outf[((size_t)(b * 18 + o) * H + hy) * W + hx] = vv + pA[o];
            } else if (o < 27) {
              const float z = vv + pA[o];
              out1[((size_t)(b * 9 + (o - 18)) * H + hy) * W + hx] = 2.f / (1.f + expf(-z));
            }
          } else {
            const size_t oi = (((size_t)(b * C + o)) << 14) + hy * W + hx;
            const float s  = pA[o] * rsqrtf(pV[o] + 1e-5f);
            const float sh = pB[o] - pM[o] * s;
            outf[oi] = vv * s + sh + resid[oi];
          }
        }
      }
    }
  }
}

// NCHW fp32 -> NHWC bf16 transpose
__global__ __launch_bounds__(256, 4)
void xcvt2(const float* __restrict__ x, unsigned short* __restrict__ xb)
{
  const int b    = blockIdx.y;
  const int pos  = blockIdx.x * 16 + (threadIdx.x >> 4);
  const int coct = threadIdx.x & 15;
  const float* __restrict__ xp = x + (((size_t)b * C + coct * 8) << 14) + pos;
  ushort8v o;
  #pragma unroll
  for (int j = 0; j < 8; ++j) o[j] = f2bf(xp[(size_t)j << 14]);
  *(ushort8v*)(xb + (((size_t)b << 14) + pos) * C + coct * 8) = o;
}

// Swizzled weights, tap-major chunks: wS[((ch*NT+ot)*64+lane)*8+j] =
// w[o=ot*16+(lane&15)][c=(ch&3)*32+(lane>>4)*8+j][tap=ch>>2] (ch<36);
// ch==36: BN-shift col (kj=(lane>>4)*8+j < 9), layer-1 only.
__global__ void prep5(const float* __restrict__ w1, const float* __restrict__ w2,
                      const float* __restrict__ ow1, const float* __restrict__ mw1,
                      const float* __restrict__ ob1, const float* __restrict__ mb1,
                      const float* __restrict__ ow2, const float* __restrict__ mw2,
                      const float* __restrict__ ob2, const float* __restrict__ mb2,
                      const float* __restrict__ g, const float* __restrict__ bb,
                      const float* __restrict__ m, const float* __restrict__ v,
                      unsigned short* __restrict__ wb1, unsigned short* __restrict__ wb2,
                      unsigned short* __restrict__ wom1, unsigned short* __restrict__ wom2,
                      float* __restrict__ bias1, float* __restrict__ bias2)
{
  const int i = blockIdx.x * 256 + threadIdx.x;
  if (i < 128 * KT2) {              // deform, NT=8
    const int j = i & 7, lane = (i >> 3) & 63, ot = (i >> 9) & 7, ch = i >> 12;
    const int o = ot * 16 + (lane & 15);
    const int qj = ((lane >> 4) << 3) + j;
    unsigned short v1 = 0, v2 = 0;
    if (ch < 36) {
      const int tap = ch >> 2;
      const int c   = ((ch & 3) << 5) + qj;
      const float s = g[c] * rsqrtf(v[c] + 1e-5f);
      v1 = f2bf(w1[(size_t)(o * 128 + c) * 9 + tap] * s);
      v2 = f2bf(w2[(size_t)(o * 128 + c) * 9 + tap]);
    } else if (qj < KK) {
      float acc = 0.f;
      for (int c = 0; c < 128; ++c) {
        const float s  = g[c] * rsqrtf(v[c] + 1e-5f);
        const float sh = bb[c] - m[c] * s;
        acc += w1[(size_t)(o * 128 + c) * 9 + qj] * sh;
      }
      v1 = f2bf(acc);
    }
    wb1[i] = v1; wb2[i] = v2;
  }
  if (i < 32 * KT2) {               // offset/mask, NT=2
    const int j = i & 7, lane = (i >> 3) & 63, ot = (i >> 9) & 1, ch = i >> 10;
    const int o = ot * 16 + (lane & 15);
    const int qj = ((lane >> 4) << 3) + j;
    unsigned short v1 = 0, v2 = 0;
    if (ch < 36) {
      const int tap = ch >> 2;
      const int c   = ((ch & 3) << 5) + qj;
      const float s = g[c] * rsqrtf(v[c] + 1e-5f);
      if (o < 18) {
        v1 = f2bf(ow1[(size_t)(o * 128 + c) * 9 + tap] * s);
        v2 = f2bf(ow2[(size_t)(o * 128 + c) * 9 + tap]);
      } else if (o < 27) {
        v1 = f2bf(mw1[(size_t)((o - 18) * 128 + c) * 9 + tap] * s);
        v2 = f2bf(mw2[(size_t)((o - 18) * 128 + c) * 9 + tap]);
      }
    } else if (qj < KK && o < 27) {
      const float* wsrc = (o < 18) ? ow1 + (size_t)o * 1152
                                   : mw1 + (size_t)(o - 18) * 1152;
      float acc = 0.f;
      for (int c = 0; c < 128; ++c) {
        const float s  = g[c] * rsqrtf(v[c] + 1e-5f);
        const float sh = bb[c] - m[c] * s;
        acc += wsrc[(size_t)c * 9 + qj] * sh;
      }
      v1 = f2bf(acc);
    }
    wom1[i] = v1; wom2[i] = v2;
  }
  if (i < 32) {
    float b1 = 0.f, b2 = 0.f;
    if (i < 18)      { b1 = ob1[i];      b2 = ob2[i]; }
    else if (i < 27) { b1 = mb1[i - 18]; b2 = mb2[i - 18]; }
    bias1[i] = b1; bias2[i] = b2;
  }
}

extern "C" void kernel_launch(void* const* d_in, const int* in_sizes, int n_in,
                              void* d_out, int out_size, void* d_ws, size_t ws_size,
                              hipStream_t stream)
{
  const float* x     = (const float*)d_in[0];
  const float* bn1g  = (const float*)d_in[1];
  const float* bn1b  = (const float*)d_in[2];
  const float* bn1m  = (const float*)d_in[3];
  const float* bn1v  = (const float*)d_in[4];
  const float* ow1   = (const float*)d_in[5];
  const float* ob1   = (const float*)d_in[6];
  const float* mw1   = (const float*)d_in[7];
  const float* mb1   = (const float*)d_in[8];
  const float* w1    = (const float*)d_in[9];
  const float* alpha = (const float*)d_in[10];
  const float* ow2   = (const float*)d_in[11];
  const float* ob2   = (const float*)d_in[12];
  const float* mw2   = (const float*)d_in[13];
  const float* mb2   = (const float*)d_in[14];
  const float* w2    = (const float*)d_in[15];
  const float* bn2g  = (const float*)d_in[16];
  const float* bn2b  = (const float*)d_in[17];
  const float* bn2m  = (const float*)d_in[18];
  const float* bn2v  = (const float*)d_in[19];
  float* out = (float*)d_out;

  char* wsp = (char*)d_ws;
  unsigned short* xbf  = (unsigned short*)(wsp);             // NHWC bf16, 16777216
  unsigned short* r2bf = (unsigned short*)(wsp + 16777216);  // NHWC bf16, 16777216
  float* offb = (float*)(wsp + 33554432);                    // 4718592
  float* mskb = (float*)(wsp + 38273024);                    // 2359296
  unsigned short* wb1  = (unsigned short*)(wsp + 40632320);  // 303104
  unsigned short* wb2  = (unsigned short*)(wsp + 40935424);  // 303104
  unsigned short* wom1 = (unsigned short*)(wsp + 41238528);  // 75776
  unsigned short* wom2 = (unsigned short*)(wsp + 41314304);  // 75776
  float* bias1 = (float*)(wsp + 41390080);
  float* bias2 = (float*)(wsp + 41390208);

  xcvt2<<<dim3(1024, 4), 256, 0, stream>>>(x, xbf);
  prep5<<<(128 * KT2 + 255) / 256, 256, 0, stream>>>(
      w1, w2, ow1, mw1, ob1, mb1, ow2, mw2, ob2, mb2,
      bn1g, bn1b, bn1m, bn1v, wb1, wb2, wom1, wom2, bias1, bias2);

  dim3 grid(2048);
  dim3 blk(64);
  // layer 1
  gemm7<0, true><<<grid, blk, 0, stream>>>(xbf, wom1, nullptr, nullptr, bias1,
      nullptr, nullptr, nullptr, nullptr, offb, nullptr, mskb);
  gemm7<1, true><<<grid, blk, 0, stream>>>(xbf, wb1, offb, mskb, alpha,
      nullptr, nullptr, nullptr, nullptr, nullptr, r2bf, nullptr);
  // layer 2
  gemm7<0, false><<<grid, blk, 0, stream>>>(r2bf, wom2, nullptr, nullptr, bias2,
      nullptr, nullptr, nullptr, nullptr, offb, nullptr, mskb);
  gemm7<2, false><<<grid, blk, 0, stream>>>(r2bf, wb2, offb, mskb, bn2g,
      bn2b, bn2m, bn2v, x, out, nullptr, nullptr);
}